// Round 2
// baseline (2401.070 us; speedup 1.0000x reference)
//
#include <hip/hip_runtime.h>
#include <stdint.h>

typedef unsigned short u16;
typedef short short8 __attribute__((ext_vector_type(8)));
typedef float f32x4 __attribute__((ext_vector_type(4)));

// ---------- bf16 helpers (manual, toolchain-version-proof) ----------
__device__ __forceinline__ u16 f2bf(float f) {
  union { float f; unsigned u; } v; v.f = f;
  unsigned u = v.u;
  u += 0x7FFFu + ((u >> 16) & 1u);   // RNE
  return (u16)(u >> 16);
}
__device__ __forceinline__ float bf2f(u16 h) {
  union { unsigned u; float f; } v; v.u = ((unsigned)h) << 16;
  return v.f;
}

// async global->LDS, 16B per lane; LDS dest = wave-uniform base + lane*16
__device__ __forceinline__ void async16(const void* g, void* l) {
  __builtin_amdgcn_global_load_lds(
      (const __attribute__((address_space(1))) unsigned int*)g,
      (__attribute__((address_space(3))) unsigned int*)l, 16, 0, 0);
}

// ---------- f32 -> bf16 conversion (weight pre-pass) ----------
__global__ __launch_bounds__(256)
void cvt_f32_bf16(const float* __restrict__ in, u16* __restrict__ out, long n) {
  const long stride = (long)gridDim.x * blockDim.x * 4;
  for (long i = ((long)blockIdx.x * blockDim.x + threadIdx.x) * 4; i < n; i += stride) {
    float4 f = *(const float4*)&in[i];
    ushort4 o; o.x = f2bf(f.x); o.y = f2bf(f.y); o.z = f2bf(f.z); o.w = f2bf(f.w);
    *(ushort4*)&out[i] = o;
  }
}

// ---------- LayerNorm: f32 in -> bf16 out (row = 4096), coalesced ----------
__global__ __launch_bounds__(256)
void ln_kernel(const float* __restrict__ in, const float* __restrict__ w,
               u16* __restrict__ out) {
  const int row = blockIdx.x;
  const int tid = threadIdx.x;
  const float* rp = in + (size_t)row * 4096;
  float4 v[4];
  float s = 0.f, sq = 0.f;
#pragma unroll
  for (int i = 0; i < 4; ++i) {
    v[i] = *(const float4*)&rp[i * 1024 + tid * 4];     // lane-contiguous
    s += v[i].x + v[i].y + v[i].z + v[i].w;
    sq += v[i].x * v[i].x + v[i].y * v[i].y + v[i].z * v[i].z + v[i].w * v[i].w;
  }
#pragma unroll
  for (int off = 32; off; off >>= 1) {
    s += __shfl_down(s, off);
    sq += __shfl_down(sq, off);
  }
  __shared__ float red[8];
  if ((tid & 63) == 0) { red[tid >> 6] = s; red[4 + (tid >> 6)] = sq; }
  __syncthreads();
  s  = red[0] + red[1] + red[2] + red[3];
  sq = red[4] + red[5] + red[6] + red[7];
  const float mean = s * (1.0f / 4096.0f);
  const float var  = sq * (1.0f / 4096.0f) - mean * mean;
  const float rstd = rsqrtf(var + 1e-5f);
  u16* op = out + (size_t)row * 4096;
#pragma unroll
  for (int i = 0; i < 4; ++i) {
    const int c = i * 1024 + tid * 4;
    ushort4 o;
    o.x = f2bf((v[i].x - mean) * rstd * w[c + 0]);
    o.y = f2bf((v[i].y - mean) * rstd * w[c + 1]);
    o.z = f2bf((v[i].z - mean) * rstd * w[c + 2]);
    o.w = f2bf((v[i].w - mean) * rstd * w[c + 3]);
    *(ushort4*)&op[c] = o;
  }
}

// ---------- GEMM: C[m,n] = sum_k A[m,k]*B[n,k], A bf16 [M,K], B [N,K] ----------
// MODE 0: C bf16.  MODE 1: C f32 = res + acc.  MODE 2: KV split (k + v^T).
// BF16B 1: B is bf16, async staging.  BF16B 0: B is f32, inline convert.
template<int MODE, int BF16B>
__global__ __launch_bounds__(256)
void gemm_bt(const u16* __restrict__ A, const void* __restrict__ Bsrc,
             void* __restrict__ Cdst, const float* __restrict__ res,
             u16* __restrict__ vt, int M, int N, int K)
{
  __shared__ u16 As[4096];   // [128][32]
  __shared__ u16 Bs[4096];   // [128][32]
  const int tid  = threadIdx.x;
  const int wave = tid >> 6;
  const int lane = tid & 63;
  const int lr = lane & 15, lq = lane >> 4;
  const int m0 = blockIdx.y * 128, n0 = blockIdx.x * 128;
  const int wm = (wave >> 1) * 64, wn = (wave & 1) * 64;

  f32x4 acc[4][4] = {};

  const int st_m = tid >> 2;          // 0..63 (16B async staging)
  const int st_k = (tid & 3) * 8;
  const int bm_n = tid >> 3;          // 0..31 (f32 manual staging)
  const int bm_k = (tid & 7) * 4;

  for (int k0 = 0; k0 < K; k0 += 32) {
#pragma unroll
    for (int p = 0; p < 2; ++p)
      async16(A + (size_t)(m0 + p * 64 + st_m) * K + (k0 + st_k),
              &As[p * 2048 + wave * 512]);
    if (BF16B) {
      const u16* Bb = (const u16*)Bsrc;
#pragma unroll
      for (int p = 0; p < 2; ++p)
        async16(Bb + (size_t)(n0 + p * 64 + st_m) * K + (k0 + st_k),
                &Bs[p * 2048 + wave * 512]);
    } else {
      const float* Bf = (const float*)Bsrc;
#pragma unroll
      for (int p = 0; p < 4; ++p) {
        float4 f = *(const float4*)(Bf + (size_t)(n0 + p * 32 + bm_n) * K + (k0 + bm_k));
        ushort4 o; o.x = f2bf(f.x); o.y = f2bf(f.y); o.z = f2bf(f.z); o.w = f2bf(f.w);
        *(ushort4*)&Bs[(p * 32 + bm_n) * 32 + bm_k] = o;
      }
    }
    __syncthreads();
    short8 af[4], bfr[4];
#pragma unroll
    for (int i = 0; i < 4; ++i) af[i]  = *(const short8*)&As[(wm + i * 16 + lr) * 32 + lq * 8];
#pragma unroll
    for (int j = 0; j < 4; ++j) bfr[j] = *(const short8*)&Bs[(wn + j * 16 + lr) * 32 + lq * 8];
#pragma unroll
    for (int i = 0; i < 4; ++i)
#pragma unroll
      for (int j = 0; j < 4; ++j)
        acc[i][j] = __builtin_amdgcn_mfma_f32_16x16x32_bf16(af[i], bfr[j], acc[i][j], 0, 0, 0);
    __syncthreads();
  }

#pragma unroll
  for (int i = 0; i < 4; ++i)
#pragma unroll
    for (int j = 0; j < 4; ++j)
#pragma unroll
      for (int r = 0; r < 4; ++r) {
        const int gr = m0 + wm + i * 16 + lq * 4 + r;   // C row = (lane>>4)*4+reg
        const int gc = n0 + wn + j * 16 + lr;           // C col = lane&15
        const float v = acc[i][j][r];
        if (MODE == 0) {
          ((u16*)Cdst)[(size_t)gr * N + gc] = f2bf(v);
        } else if (MODE == 1) {
          ((float*)Cdst)[(size_t)gr * N + gc] = res[(size_t)gr * N + gc] + v;
        } else {
          if (gc < 128) ((u16*)Cdst)[gr * 128 + gc] = f2bf(v);          // k [t][d]
          else          vt[(size_t)(gc - 128) * 2048 + gr] = f2bf(v);   // v^T [d][t]
        }
      }
}

// ---------- ALiBi causal flash attention (MQA: shared K/V) ----------
// grid (32, 32heads), 256 thr; wave handles 16 Q rows (s0..s0+15).
__global__ __launch_bounds__(256)
void attn_kernel(const u16* __restrict__ q, const u16* __restrict__ kbuf,
                 const u16* __restrict__ vt, u16* __restrict__ attnb)
{
  __shared__ u16 P[4][16 * 32];
  const int tid = threadIdx.x;
  const int wave = tid >> 6, lane = tid & 63;
  const int lr = lane & 15, lq = lane >> 4;
  const int h = blockIdx.y;
  const int s0 = blockIdx.x * 64 + wave * 16;
  const float slope = exp2f(-0.25f * (float)(h + 1));
  const float scale = 0.08838834764831845f;   // 1/sqrt(128)

  short8 qf[4];
#pragma unroll
  for (int kk = 0; kk < 4; ++kk)
    qf[kk] = *(const short8*)&q[(size_t)(s0 + lr) * 4096 + h * 128 + kk * 32 + lq * 8];

  f32x4 o[8];
#pragma unroll
  for (int j = 0; j < 8; ++j) o[j] = (f32x4){0.f, 0.f, 0.f, 0.f};
  float mrow[4] = {-3e38f, -3e38f, -3e38f, -3e38f};
  float lrow[4] = {0.f, 0.f, 0.f, 0.f};
  const int tend = s0 + 16;

  for (int t0 = 0; t0 < tend; t0 += 32) {
    float sval[2][4];
#pragma unroll
    for (int c = 0; c < 2; ++c) {
      const int tc = t0 + c * 16;
      f32x4 sc = (f32x4){0.f, 0.f, 0.f, 0.f};
      if (tc < tend) {
#pragma unroll
        for (int kk = 0; kk < 4; ++kk) {
          short8 kf = *(const short8*)&kbuf[(size_t)(tc + lr) * 128 + kk * 32 + lq * 8];
          sc = __builtin_amdgcn_mfma_f32_16x16x32_bf16(qf[kk], kf, sc, 0, 0, 0);
        }
      }
      const int t = tc + lr;
#pragma unroll
      for (int r = 0; r < 4; ++r) {
        const int s = s0 + lq * 4 + r;
        sval[c][r] = (tc < tend && t <= s)
                     ? (sc[r] * scale + slope * (float)(t - s)) : -3e38f;
      }
    }
    float alpha_r[4];
#pragma unroll
    for (int r = 0; r < 4; ++r) {
      float mx = fmaxf(sval[0][r], sval[1][r]);
      mx = fmaxf(mx, __shfl_xor(mx, 1));
      mx = fmaxf(mx, __shfl_xor(mx, 2));
      mx = fmaxf(mx, __shfl_xor(mx, 4));
      mx = fmaxf(mx, __shfl_xor(mx, 8));
      const float mnew = fmaxf(mrow[r], mx);
      alpha_r[r] = __expf(mrow[r] - mnew);
      mrow[r] = mnew;
      const float p0 = __expf(sval[0][r] - mnew);   // masked -> exp(-huge) = 0
      const float p1 = __expf(sval[1][r] - mnew);
      float rs = p0 + p1;
      rs += __shfl_xor(rs, 1);
      rs += __shfl_xor(rs, 2);
      rs += __shfl_xor(rs, 4);
      rs += __shfl_xor(rs, 8);
      lrow[r] = lrow[r] * alpha_r[r] + rs;
      P[wave][(lq * 4 + r) * 32 + lr]      = f2bf(p0);   // C-layout -> LDS
      P[wave][(lq * 4 + r) * 32 + 16 + lr] = f2bf(p1);
    }
    __threadfence_block();
    const short8 pf = *(const short8*)&P[wave][lr * 32 + lq * 8];  // A-layout read
#pragma unroll
    for (int j = 0; j < 8; ++j)
#pragma unroll
      for (int r = 0; r < 4; ++r) o[j][r] *= alpha_r[r];
#pragma unroll
    for (int j = 0; j < 8; ++j) {
      const short8 vf = *(const short8*)&vt[(size_t)(j * 16 + lr) * 2048 + t0 + lq * 8];
      o[j] = __builtin_amdgcn_mfma_f32_16x16x32_bf16(pf, vf, o[j], 0, 0, 0);
    }
  }

#pragma unroll
  for (int j = 0; j < 8; ++j)
#pragma unroll
    for (int r = 0; r < 4; ++r) {
      const int s = s0 + lq * 4 + r;
      const int d = j * 16 + lr;
      attnb[(size_t)s * 4096 + h * 128 + d] = f2bf(o[j][r] / lrow[r]);
    }
}

// ---------- SwiGLU: act = silu(g)*u from gu [2048][22016] ----------
__global__ __launch_bounds__(256)
void silu_mul_kernel(const u16* __restrict__ gu, u16* __restrict__ act) {
  const int stride = gridDim.x * blockDim.x;
  for (int i = blockIdx.x * blockDim.x + threadIdx.x; i < 2048 * 1376; i += stride) {
    const int row = i / 1376;
    const int c8 = (i - row * 1376) * 8;
    ushort4 ga = *(const ushort4*)&gu[(size_t)row * 22016 + c8];
    ushort4 gb = *(const ushort4*)&gu[(size_t)row * 22016 + c8 + 4];
    ushort4 ua = *(const ushort4*)&gu[(size_t)row * 22016 + 11008 + c8];
    ushort4 ub = *(const ushort4*)&gu[(size_t)row * 22016 + 11008 + c8 + 4];
    u16 r[8];
    const u16 gv[8] = {ga.x, ga.y, ga.z, ga.w, gb.x, gb.y, gb.z, gb.w};
    const u16 uv[8] = {ua.x, ua.y, ua.z, ua.w, ub.x, ub.y, ub.z, ub.w};
#pragma unroll
    for (int e = 0; e < 8; ++e) {
      const float g = bf2f(gv[e]), u = bf2f(uv[e]);
      r[e] = f2bf(g * u / (1.0f + __expf(-g)));
    }
    ushort4 o0 = {r[0], r[1], r[2], r[3]}, o1 = {r[4], r[5], r[6], r[7]};
    *(ushort4*)&act[(size_t)row * 11008 + c8]     = o0;
    *(ushort4*)&act[(size_t)row * 11008 + c8 + 4] = o1;
  }
}

extern "C" void kernel_launch(void* const* d_in, const int* in_sizes, int n_in,
                              void* d_out, int out_size, void* d_ws, size_t ws_size,
                              hipStream_t stream)
{
  const float* hidden = (const float*)d_in[0];
  const float* ln1w   = (const float*)d_in[1];
  const float* ln2w   = (const float*)d_in[2];
  const float* Wq     = (const float*)d_in[3];
  const float* Wkv    = (const float*)d_in[4];
  const float* Wo     = (const float*)d_in[5];
  const float* Wgu    = (const float*)d_in[6];
  const float* Wdown  = (const float*)d_in[7];
  float* out = (float*)d_out;

  // Compact layout with liveness overlap (base footprint 185,597,952 B):
  //   [0,32M)      hb   f32 2048x4096          (live: Wo epilogue -> end)
  //   [32M,48M)    x/y  bf16 2048x4096         (live: ln1 -> Wgu GEMM)
  //   [48M,64M)    q    bf16 2048x4096         (dead after attention)
  //   [64M,80M)    attnb bf16 2048x4096        (dead after Wo GEMM)
  //   [80M,80.5M)  kbuf bf16 2048x128
  //   [80.5M,81M)  vt   bf16 128x2048
  //   [48M,134M)   gu   bf16 2048x22016        (overlaps q/attnb/kv — dead by then)
  //   [134M,177M)  act  bf16 2048x11008
  char* wp = (char*)d_ws;
  float* hb  = (float*)(wp);                    // 33,554,432
  u16* x     = (u16*)(wp + 33554432);           // 16,777,216
  u16* q     = (u16*)(wp + 50331648);           // 16,777,216
  u16* attnb = (u16*)(wp + 67108864);           // 16,777,216
  u16* kbuf  = (u16*)(wp + 83886080);           //    524,288
  u16* vt    = (u16*)(wp + 84410368);           //    524,288
  u16* gu    = (u16*)(wp + 50331648);           // 90,177,536 (overlap)
  u16* act   = (u16*)(wp + 140509184);          // 45,088,768 -> end 185,597,952
  u16* y = x;

  const size_t BASE_END = 185597952;
  const size_t FAST_END = BASE_END + 339738624;  // + bf16 weights
  const bool fast = ws_size >= FAST_END;

  u16 *Wqb = 0, *Wkvb = 0, *Wob = 0, *Wgub = 0, *Wdb = 0;
  if (fast) {
    char* fp = wp + BASE_END;
    Wqb  = (u16*)(fp);                //  33,554,432
    Wkvb = (u16*)(fp + 33554432);     //   2,097,152
    Wob  = (u16*)(fp + 35651584);     //  33,554,432
    Wgub = (u16*)(fp + 69206016);     // 180,355,072
    Wdb  = (u16*)(fp + 249561088);    //  90,177,536
    cvt_f32_bf16<<<4096, 256, 0, stream>>>(Wq,    Wqb,  16777216L);
    cvt_f32_bf16<<<256,  256, 0, stream>>>(Wkv,   Wkvb, 1048576L);
    cvt_f32_bf16<<<4096, 256, 0, stream>>>(Wo,    Wob,  16777216L);
    cvt_f32_bf16<<<8192, 256, 0, stream>>>(Wgu,   Wgub, 90177536L);
    cvt_f32_bf16<<<8192, 256, 0, stream>>>(Wdown, Wdb,  45088768L);
  }

  ln_kernel<<<2048, 256, 0, stream>>>(hidden, ln1w, x);

  if (fast) {
    gemm_bt<0, 1><<<dim3(32, 16), 256, 0, stream>>>(x, Wqb,  q,    0, 0,  2048, 4096, 4096);
    gemm_bt<2, 1><<<dim3(2, 16),  256, 0, stream>>>(x, Wkvb, kbuf, 0, vt, 2048, 256,  4096);
  } else {
    gemm_bt<0, 0><<<dim3(32, 16), 256, 0, stream>>>(x, Wq,  q,    0, 0,  2048, 4096, 4096);
    gemm_bt<2, 0><<<dim3(2, 16),  256, 0, stream>>>(x, Wkv, kbuf, 0, vt, 2048, 256,  4096);
  }

  attn_kernel<<<dim3(32, 32), 256, 0, stream>>>(q, kbuf, vt, attnb);

  if (fast)
    gemm_bt<1, 1><<<dim3(32, 16), 256, 0, stream>>>(attnb, Wob, hb, hidden, 0, 2048, 4096, 4096);
  else
    gemm_bt<1, 0><<<dim3(32, 16), 256, 0, stream>>>(attnb, Wo,  hb, hidden, 0, 2048, 4096, 4096);

  ln_kernel<<<2048, 256, 0, stream>>>(hb, ln2w, y);

  if (fast)
    gemm_bt<0, 1><<<dim3(172, 16), 256, 0, stream>>>(y, Wgub, gu, 0, 0, 2048, 22016, 4096);
  else
    gemm_bt<0, 0><<<dim3(172, 16), 256, 0, stream>>>(y, Wgu,  gu, 0, 0, 2048, 22016, 4096);

  silu_mul_kernel<<<1024, 256, 0, stream>>>(gu, act);

  if (fast)
    gemm_bt<1, 1><<<dim3(32, 16), 256, 0, stream>>>(act, Wdb,   out, hb, 0, 2048, 4096, 11008);
  else
    gemm_bt<1, 0><<<dim3(32, 16), 256, 0, stream>>>(act, Wdown, out, hb, 0, 2048, 4096, 11008);
}